// Round 12
// baseline (254.263 us; speedup 1.0000x reference)
//
#include <hip/hip_runtime.h>

#define C_IN   512
#define C_INT  128
#define NBUCK  8192
#define SEG    32
#define NSEG   256   // 8192 / SEG

typedef short short8 __attribute__((ext_vector_type(8)));
typedef float floatx4 __attribute__((ext_vector_type(4)));

// ---------- helpers ----------

__device__ __forceinline__ int bucket_of(float v, float bmin, float inv_w) {
    float fk = (v - bmin) * inv_w;
    fk = fminf(fmaxf(fk, 0.f), (float)(NBUCK - 1));
    return (int)fk;
}

__device__ __forceinline__ short bf16rnd(float v) {
    unsigned u = __float_as_uint(v);
    return (short)((u + 0x7fffu + ((u >> 16) & 1u)) >> 16);
}

// ---------- K1: prep (verified r5; + sync-counter zeroing) ----------

__global__ __launch_bounds__(256) void prep_kernel(
        const float* __restrict__ Wt, const float* __restrict__ Wp,
        const float* __restrict__ Wg, const float* __restrict__ wcat,
        const float* __restrict__ bt, const float* __restrict__ bp,
        float* __restrict__ ut, float* __restrict__ up, float* __restrict__ scal,
        unsigned short* __restrict__ WgT, unsigned* __restrict__ sync) {
    int t = threadIdx.x, bk = blockIdx.x;
    if (bk < 16) {
        const float* W  = (bk < 8) ? Wt : Wp;
        const float* wv = wcat + ((bk < 8) ? 0 : C_INT);
        float* dst      = (bk < 8) ? ut : up;
        int k = (bk & 7) * 64 + (t >> 2);
        int q = t & 3;
        const float4* row = (const float4*)(W + (size_t)k * C_INT);
        const float4* cv4 = (const float4*)wv;
        float s = 0.f;
        #pragma unroll
        for (int i = 0; i < 8; ++i) {
            float4 a = row[q * 8 + i];
            float4 c = cv4[q * 8 + i];
            s += a.x * c.x + a.y * c.y + a.z * c.z + a.w * c.w;
        }
        s += __shfl_xor(s, 1);
        s += __shfl_xor(s, 2);
        if (q == 0) dst[k] = s;
    } else if (bk == 16) {
        float s1p = (t < C_INT) ? bt[t] * wcat[t] : 0.f;
        float s2p = (t < C_INT) ? bp[t] * wcat[C_INT + t] : 0.f;
        for (int off = 32; off; off >>= 1) {
            s1p += __shfl_down(s1p, off);
            s2p += __shfl_down(s2p, off);
        }
        __shared__ float red[8];
        int w = t >> 6, lane = t & 63;
        if (lane == 0) { red[w] = s1p; red[4 + w] = s2p; }
        __syncthreads();
        if (t == 0) {
            scal[0] = red[0] + red[1] + red[2] + red[3];
            scal[1] = red[4] + red[5] + red[6] + red[7];
            sync[0] = 0u; sync[1] = 0u;
        }
    } else {
        __shared__ float tile[64][132];
        int kb = (bk - 17) * 64;
        #pragma unroll
        for (int it = 0; it < 8; ++it) {
            int idx = it * 256 + t;
            int r = idx >> 5, c4 = idx & 31;
            *(float4*)&tile[r][c4 * 4] =
                ((const float4*)(Wg + (size_t)(kb + r) * C_INT))[c4];
        }
        __syncthreads();
        int n = t & 127, kc = (t >> 7) * 32;
        unsigned pk[16];
        #pragma unroll
        for (int i = 0; i < 16; ++i) {
            unsigned lo = (unsigned short)bf16rnd(tile[kc + 2 * i][n]);
            unsigned hi = (unsigned short)bf16rnd(tile[kc + 2 * i + 1][n]);
            pk[i] = lo | (hi << 16);
        }
        uint4* dst = (uint4*)(WgT + (size_t)n * C_IN + kb + kc);
        #pragma unroll
        for (int i2 = 0; i2 < 4; ++i2) dst[i2] = *(uint4*)&pk[i2 * 4];
    }
}

// ---------- K2: MFMA gemm, col-split (verified r11, unchanged) ----------

#define RSTR 66

__global__ __launch_bounds__(256) void gemm_mfma(
        const float* __restrict__ x, const unsigned short* __restrict__ WgT,
        const float* __restrict__ bg,
        const float* __restrict__ ut, const float* __restrict__ up,
        const float* __restrict__ scal,
        _Float16* __restrict__ g, float* __restrict__ a, float* __restrict__ b) {
    __shared__ float red[3][20][RSTR];
    int tid = threadIdx.x;
    int lane = tid & 63, wv = tid >> 6;
    int bx = blockIdx.x;
    int i0 = (bx >> 1) * 16;
    int cg = bx & 1;
    int m = lane & 15, q = lane >> 4;
    floatx4 accg[4] = {};
    floatx4 accab = {};
    const float* xrow = x + (size_t)(i0 + m) * C_IN + q * 8;
    const float* absrc = (m == 0) ? ut : up;
    #pragma unroll
    for (int ks = 0; ks < 4; ++ks) {
        int k0 = (wv * 4 + ks) * 32;
        float4 f0 = *(const float4*)(xrow + k0);
        float4 f1 = *(const float4*)(xrow + k0 + 4);
        short8 af;
        af[0] = bf16rnd(f0.x); af[1] = bf16rnd(f0.y);
        af[2] = bf16rnd(f0.z); af[3] = bf16rnd(f0.w);
        af[4] = bf16rnd(f1.x); af[5] = bf16rnd(f1.y);
        af[6] = bf16rnd(f1.z); af[7] = bf16rnd(f1.w);
        if (cg == 0) {
            short8 abf = {};
            if (m < 2) {
                float4 u0 = *(const float4*)(absrc + k0 + q * 8);
                float4 u1 = *(const float4*)(absrc + k0 + q * 8 + 4);
                abf[0] = bf16rnd(u0.x); abf[1] = bf16rnd(u0.y);
                abf[2] = bf16rnd(u0.z); abf[3] = bf16rnd(u0.w);
                abf[4] = bf16rnd(u1.x); abf[5] = bf16rnd(u1.y);
                abf[6] = bf16rnd(u1.z); abf[7] = bf16rnd(u1.w);
            }
            accab = __builtin_amdgcn_mfma_f32_16x16x32_bf16(af, abf, accab, 0, 0, 0);
        }
        #pragma unroll
        for (int f = 0; f < 4; ++f) {
            short8 bfr = *(const short8*)(WgT + (size_t)(cg * 64 + f * 16 + m) * C_IN + k0 + q * 8);
            accg[f] = __builtin_amdgcn_mfma_f32_16x16x32_bf16(af, bfr, accg[f], 0, 0, 0);
        }
    }
    if (wv) {
        #pragma unroll
        for (int f = 0; f < 4; ++f)
            #pragma unroll
            for (int r = 0; r < 4; ++r)
                red[wv - 1][f * 4 + r][lane] = accg[f][r];
        #pragma unroll
        for (int r = 0; r < 4; ++r)
            red[wv - 1][16 + r][lane] = accab[r];
    }
    __syncthreads();
    if (wv == 0) {
        #pragma unroll
        for (int w = 0; w < 3; ++w) {
            #pragma unroll
            for (int f = 0; f < 4; ++f)
                #pragma unroll
                for (int r = 0; r < 4; ++r)
                    accg[f][r] += red[w][f * 4 + r][lane];
            #pragma unroll
            for (int r = 0; r < 4; ++r)
                accab[r] += red[w][16 + r][lane];
        }
        #pragma unroll
        for (int f = 0; f < 4; ++f) {
            int col = cg * 64 + f * 16 + m;
            float bgv = bg[col];
            #pragma unroll
            for (int r = 0; r < 4; ++r) {
                int row = i0 + q * 4 + r;
                g[(size_t)row * C_INT + col] = (_Float16)(accg[f][r] + bgv);
            }
        }
        if (cg == 0 && m < 2) {
            float off = m ? scal[1] : scal[0];
            float* dst = m ? b : a;
            #pragma unroll
            for (int r = 0; r < 4; ++r) dst[i0 + q * 4 + r] = accab[r] + off;
        }
    }
}

// ---------- K3: fused post1: sort (block 0) -> segsum -> suffix -> Pr expand ----------
// 256 blocks x 1024 threads, ~48.5 KB LDS -> all blocks provably co-resident
// (>=1 block/CU on 256 CUs); device-scope atomic barriers via sync[0..1].

__global__ __launch_bounds__(1024) void post1_kernel(
        const _Float16* __restrict__ g, const float* __restrict__ b,
        float* __restrict__ scal,
        unsigned* __restrict__ offs_g, unsigned short* __restrict__ perm_g,
        float* __restrict__ bsort_g,
        float* __restrict__ seg1, float* __restrict__ seg2,
        float* __restrict__ Pr1, float* __restrict__ Pr2,
        unsigned* __restrict__ sync) {
    __shared__ __align__(16) unsigned char smem[49408];
    // sort-phase layout (block 0 only)
    unsigned*       oh  = (unsigned*)(smem);            // [4096] packed u16 pairs
    unsigned*       cur = (unsigned*)(smem + 16384);    // [4096]
    unsigned short* ls  = (unsigned short*)(smem + 32768);  // [8192]
    unsigned*       wtu = (unsigned*)(smem + 49152);    // [16]
    float*          smn = (float*)(smem + 49216);       // [16]
    float*          smx = (float*)(smem + 49280);       // [16]
    // compute-phase layout (aliases sort arrays; phases separated by barrier)
    float* part1 = (float*)(smem);                      // [8][128]
    float* part2 = (float*)(smem + 4096);
    float* rs1   = (float*)(smem + 8192);
    float* rs2   = (float*)(smem + 12288);
    int*   pj    = (int*)(smem + 16384);                // [32]
    float* pb    = (float*)(smem + 16512);              // [32]

    int t = threadIdx.x, s = blockIdx.x;
    int lane = t & 63, wv = t >> 6;

    if (s == 0) {
        // ---- sort phase (r11-verified) ----
        #pragma unroll
        for (int r = 0; r < 4; ++r) { oh[t + r * 1024] = 0u; cur[t + r * 1024] = 0u; }
        float bv[8];
        float mn = 1e30f, mx = -1e30f;
        #pragma unroll
        for (int r = 0; r < 8; ++r) {
            bv[r] = b[t + r * 1024];
            mn = fminf(mn, bv[r]); mx = fmaxf(mx, bv[r]);
        }
        for (int off = 32; off; off >>= 1) {
            mn = fminf(mn, __shfl_down(mn, off));
            mx = fmaxf(mx, __shfl_down(mx, off));
        }
        if (lane == 0) { smn[wv] = mn; smx[wv] = mx; }
        __syncthreads();
        if (t == 0) {
            float gmn = smn[0], gmx = smx[0];
            #pragma unroll
            for (int i = 1; i < 16; ++i) {
                gmn = fminf(gmn, smn[i]); gmx = fmaxf(gmx, smx[i]);
            }
            float range = gmx - gmn;
            float iw = (range > 1e-30f) ? (float)NBUCK / range : 0.f;
            smn[0] = gmn; smx[0] = iw;
            scal[4] = gmn; scal[5] = iw;
        }
        __syncthreads();
        float bmin = smn[0], inv_w = smx[0];
        int kb[8];
        #pragma unroll
        for (int r = 0; r < 8; ++r) {
            kb[r] = bucket_of(bv[r], bmin, inv_w);
            atomicAdd(&oh[kb[r] >> 1], (kb[r] & 1) ? 0x10000u : 1u);
        }
        __syncthreads();
        unsigned h[8], p = 0;
        #pragma unroll
        for (int w = 0; w < 4; ++w) {
            unsigned word = oh[t * 4 + w];
            p += word & 0xffffu;  h[w * 2]     = p;
            p += word >> 16;      h[w * 2 + 1] = p;
        }
        unsigned v = p;
        #pragma unroll
        for (int d = 1; d < 64; d <<= 1) {
            unsigned u = __shfl_up(v, d);
            if (lane >= d) v += u;
        }
        if (lane == 63) wtu[wv] = v;
        __syncthreads();
        if (t < 16) {
            unsigned w = wtu[t];
            #pragma unroll
            for (int d = 1; d < 16; d <<= 1) {
                unsigned u = __shfl_up(w, d);
                if (t >= d) w += u;
            }
            wtu[t] = w;
        }
        __syncthreads();
        unsigned base = (v - p) + (wv ? wtu[wv - 1] : 0u);
        #pragma unroll
        for (int w = 0; w < 4; ++w) {
            unsigned lo = base + h[w * 2], hi = base + h[w * 2 + 1];
            oh[t * 4 + w] = lo | (hi << 16);
            offs_g[t * 8 + w * 2 + 1] = lo;
            offs_g[t * 8 + w * 2 + 2] = hi;
        }
        if (t == 0) offs_g[0] = 0u;
        __syncthreads();
        #pragma unroll
        for (int r = 0; r < 8; ++r) {
            int j = t + r * 1024;
            int k = kb[r];
            unsigned st = 0u;
            if (k > 0) {
                unsigned word = oh[(k - 1) >> 1];
                st = ((k - 1) & 1) ? (word >> 16) : (word & 0xffffu);
            }
            unsigned old = atomicAdd(&cur[k >> 1], (k & 1) ? 0x10000u : 1u);
            unsigned pos = (k & 1) ? (old >> 16) : (old & 0xffffu);
            ls[st + pos] = (unsigned short)j;
        }
        __syncthreads();
        #pragma unroll
        for (int r = 0; r < 8; ++r) {
            int e = t + r * 1024;
            int j = ls[e];
            perm_g[e] = (unsigned short)j;
            bsort_g[e] = b[j];
        }
        __threadfence();       // push sort outputs device-wide
        __syncthreads();
        if (t == 0) atomicAdd(&sync[0], 1u);
    }
    // ---- barrier 1: wait for sort ----
    if (t == 0) { while (atomicAdd(&sync[0], 0u) == 0u) {} }
    __syncthreads();
    __threadfence();

    int c = t & 127, p = t >> 7;   // 8 parts x 4 rows
    if (t < SEG) { pj[t] = perm_g[s * SEG + t]; pb[t] = bsort_g[s * SEG + t]; }
    __syncthreads();

    // segment partial sums (8-way row parallel)
    float a1 = 0.f, a2 = 0.f;
    #pragma unroll
    for (int e = p * 4; e < p * 4 + 4; ++e) {
        float gv = (float)g[(size_t)pj[e] * C_INT + c];
        a1 += gv; a2 += pb[e] * gv;
    }
    part1[p * 128 + c] = a1; part2[p * 128 + c] = a2;
    __syncthreads();
    if (p == 0) {
        float t1 = 0.f, t2 = 0.f;
        #pragma unroll
        for (int pp = 0; pp < 8; ++pp) {
            t1 += part1[pp * 128 + c]; t2 += part2[pp * 128 + c];
        }
        seg1[s * C_INT + c] = t1; seg2[s * C_INT + c] = t2;
        __threadfence();
    }
    __syncthreads();
    if (t == 0) {
        atomicAdd(&sync[1], 1u);
        while (atomicAdd(&sync[1], 0u) < (unsigned)NSEG) {}
    }
    __syncthreads();
    __threadfence();

    // suffix over later segments: thread (c,p) sums strided subset, LDS-reduce
    float r1 = 0.f, r2 = 0.f;
    for (int s2 = s + 1 + p; s2 < NSEG; s2 += 8) {
        r1 += seg1[s2 * C_INT + c];
        r2 += seg2[s2 * C_INT + c];
    }
    rs1[p * 128 + c] = r1; rs2[p * 128 + c] = r2;
    __syncthreads();
    float rseg1 = 0.f, rseg2 = 0.f;
    #pragma unroll
    for (int pp = 0; pp < 8; ++pp) {
        rseg1 += rs1[pp * 128 + c]; rseg2 += rs2[pp * 128 + c];
    }
    // add later parts of own segment
    float w1 = rseg1, w2 = rseg2;
    #pragma unroll
    for (int pp = p + 1; pp < 8; ++pp) {
        w1 += part1[pp * 128 + c]; w2 += part2[pp * 128 + c];
    }
    // serial walk over own 4 rows (bottom-up), emitting row-granular suffix
    #pragma unroll
    for (int e = p * 4 + 3; e >= p * 4; --e) {
        float gv = (float)g[(size_t)pj[e] * C_INT + c];
        w1 += gv; w2 += pb[e] * gv;
        size_t idx = (size_t)(s * SEG + e) * C_INT + c;
        Pr1[idx] = w1; Pr2[idx] = w2;
    }
    if (s == 0 && t < C_INT) {
        Pr1[(size_t)8192 * C_INT + t] = 0.f;
        Pr2[(size_t)8192 * C_INT + t] = 0.f;
    }
}

// ---------- K4: per-row output (verified r7/r11, unchanged) ----------

__global__ __launch_bounds__(128) void out_kernel(
        const float* __restrict__ a, const float* __restrict__ scal,
        const _Float16* __restrict__ g,
        const unsigned* __restrict__ offs, const unsigned short* __restrict__ perm,
        const float* __restrict__ bsort,
        const float* __restrict__ Pr1, const float* __restrict__ Pr2,
        float* __restrict__ out, float inv_n) {
    __shared__ int pj[128];
    __shared__ float pb[128];
    int i = blockIdx.x, c = threadIdx.x;
    float ai = a[i], thr = -ai;
    float bmin = scal[4], inv_w = scal[5];
    int ki = bucket_of(thr, bmin, inv_w);
    unsigned e0 = offs[ki], e1 = offs[ki + 1];
    size_t base = (size_t)e1 * C_INT + c;
    float acc = ai * Pr1[base] + Pr2[base];
    for (unsigned be = e0; be < e1; be += 128) {
        unsigned cnt = min(128u, e1 - be);
        if ((unsigned)c < cnt) { pj[c] = perm[be + c]; pb[c] = bsort[be + c]; }
        __syncthreads();
        for (unsigned r = 0; r < cnt; ++r) {
            float bj = pb[r];
            if (bj > thr)
                acc += (ai + bj) * (float)g[(size_t)pj[r] * C_INT + c];
        }
        __syncthreads();
    }
    out[(size_t)i * C_INT + c] = acc * inv_n;
}

// ---------- launch ----------

extern "C" void kernel_launch(void* const* d_in, const int* in_sizes, int n_in,
                              void* d_out, int out_size, void* d_ws, size_t ws_size,
                              hipStream_t stream) {
    const float* x    = (const float*)d_in[0];
    const float* Wg   = (const float*)d_in[1];
    const float* bg   = (const float*)d_in[2];
    const float* Wt   = (const float*)d_in[3];
    const float* bt   = (const float*)d_in[4];
    const float* Wp   = (const float*)d_in[5];
    const float* bp   = (const float*)d_in[6];
    const float* wcat = (const float*)d_in[7];
    float* out = (float*)d_out;
    int n = in_sizes[0] / C_IN;   // 8192

    char* w = (char*)d_ws;
    size_t off = 0;
    auto alloc = [&](size_t bytes) -> void* {
        void* p = w + off;
        off += (bytes + 255) & ~(size_t)255;
        return p;
    };
    float*          ut    = (float*)alloc(C_IN * 4);
    float*          up    = (float*)alloc(C_IN * 4);
    float*          scal  = (float*)alloc(32);
    unsigned*       sync  = (unsigned*)alloc(16);
    float*          a     = (float*)alloc((size_t)n * 4);
    float*          b     = (float*)alloc((size_t)n * 4);
    unsigned*       offs  = (unsigned*)alloc((size_t)(NBUCK + 1) * 4);
    unsigned short* perm  = (unsigned short*)alloc((size_t)n * 2);
    float*          bsort = (float*)alloc((size_t)n * 4);
    _Float16*       g     = (_Float16*)alloc((size_t)n * C_INT * 2);
    unsigned short* WgT   = (unsigned short*)alloc((size_t)C_INT * C_IN * 2);
    float*          seg1  = (float*)alloc((size_t)NSEG * C_INT * 4);
    float*          seg2  = (float*)alloc((size_t)NSEG * C_INT * 4);
    float*          Pr1   = (float*)alloc((size_t)(n + 1) * C_INT * 4);
    float*          Pr2   = (float*)alloc((size_t)(n + 1) * C_INT * 4);

    prep_kernel<<<25, 256, 0, stream>>>(Wt, Wp, Wg, wcat, bt, bp, ut, up, scal,
                                        WgT, sync);
    gemm_mfma<<<n / 8, 256, 0, stream>>>(x, WgT, bg, ut, up, scal, g, a, b);
    post1_kernel<<<NSEG, 1024, 0, stream>>>(g, b, scal, offs, perm, bsort,
                                            seg1, seg2, Pr1, Pr2, sync);
    out_kernel<<<n, 128, 0, stream>>>(a, scal, g, offs, perm, bsort, Pr1, Pr2,
                                      out, 1.0f / (float)n);
}

// Round 13
// 143.512 us; speedup vs baseline: 1.7717x; 1.7717x over previous
//
#include <hip/hip_runtime.h>

#define C_IN   512
#define C_INT  128
#define NBUCK  8192
#define NSEG   256           // segments = 32 buckets each (bucket-aligned!)
#define BPS    (NBUCK / NSEG)  // 32 buckets per segment

typedef short short8 __attribute__((ext_vector_type(8)));
typedef float floatx4 __attribute__((ext_vector_type(4)));

// ---------- helpers ----------

__device__ __forceinline__ int bucket_of(float v, float bmin, float inv_w) {
    float fk = (v - bmin) * inv_w;
    fk = fminf(fmaxf(fk, 0.f), (float)(NBUCK - 1));
    return (int)fk;
}

__device__ __forceinline__ short bf16rnd(float v) {
    unsigned u = __float_as_uint(v);
    return (short)((u + 0x7fffu + ((u >> 16) & 1u)) >> 16);
}

// ---------- K1: prep (verified r5/r11, sync removed) ----------

__global__ __launch_bounds__(256) void prep_kernel(
        const float* __restrict__ Wt, const float* __restrict__ Wp,
        const float* __restrict__ Wg, const float* __restrict__ wcat,
        const float* __restrict__ bt, const float* __restrict__ bp,
        float* __restrict__ ut, float* __restrict__ up, float* __restrict__ scal,
        unsigned short* __restrict__ WgT) {
    int t = threadIdx.x, bk = blockIdx.x;
    if (bk < 16) {
        const float* W  = (bk < 8) ? Wt : Wp;
        const float* wv = wcat + ((bk < 8) ? 0 : C_INT);
        float* dst      = (bk < 8) ? ut : up;
        int k = (bk & 7) * 64 + (t >> 2);
        int q = t & 3;
        const float4* row = (const float4*)(W + (size_t)k * C_INT);
        const float4* cv4 = (const float4*)wv;
        float s = 0.f;
        #pragma unroll
        for (int i = 0; i < 8; ++i) {
            float4 a = row[q * 8 + i];
            float4 c = cv4[q * 8 + i];
            s += a.x * c.x + a.y * c.y + a.z * c.z + a.w * c.w;
        }
        s += __shfl_xor(s, 1);
        s += __shfl_xor(s, 2);
        if (q == 0) dst[k] = s;
    } else if (bk == 16) {
        float s1p = (t < C_INT) ? bt[t] * wcat[t] : 0.f;
        float s2p = (t < C_INT) ? bp[t] * wcat[C_INT + t] : 0.f;
        for (int off = 32; off; off >>= 1) {
            s1p += __shfl_down(s1p, off);
            s2p += __shfl_down(s2p, off);
        }
        __shared__ float red[8];
        int w = t >> 6, lane = t & 63;
        if (lane == 0) { red[w] = s1p; red[4 + w] = s2p; }
        __syncthreads();
        if (t == 0) {
            scal[0] = red[0] + red[1] + red[2] + red[3];
            scal[1] = red[4] + red[5] + red[6] + red[7];
        }
    } else {
        __shared__ float tile[64][132];
        int kb = (bk - 17) * 64;
        #pragma unroll
        for (int it = 0; it < 8; ++it) {
            int idx = it * 256 + t;
            int r = idx >> 5, c4 = idx & 31;
            *(float4*)&tile[r][c4 * 4] =
                ((const float4*)(Wg + (size_t)(kb + r) * C_INT))[c4];
        }
        __syncthreads();
        int n = t & 127, kc = (t >> 7) * 32;
        unsigned pk[16];
        #pragma unroll
        for (int i = 0; i < 16; ++i) {
            unsigned lo = (unsigned short)bf16rnd(tile[kc + 2 * i][n]);
            unsigned hi = (unsigned short)bf16rnd(tile[kc + 2 * i + 1][n]);
            pk[i] = lo | (hi << 16);
        }
        uint4* dst = (uint4*)(WgT + (size_t)n * C_IN + kb + kc);
        #pragma unroll
        for (int i2 = 0; i2 < 4; ++i2) dst[i2] = *(uint4*)&pk[i2 * 4];
    }
}

// ---------- K2: MFMA gemm, col-split (verified r11, unchanged) ----------

#define RSTR 66

__global__ __launch_bounds__(256) void gemm_mfma(
        const float* __restrict__ x, const unsigned short* __restrict__ WgT,
        const float* __restrict__ bg,
        const float* __restrict__ ut, const float* __restrict__ up,
        const float* __restrict__ scal,
        _Float16* __restrict__ g, float* __restrict__ a, float* __restrict__ b) {
    __shared__ float red[3][20][RSTR];
    int tid = threadIdx.x;
    int lane = tid & 63, wv = tid >> 6;
    int bx = blockIdx.x;
    int i0 = (bx >> 1) * 16;
    int cg = bx & 1;
    int m = lane & 15, q = lane >> 4;
    floatx4 accg[4] = {};
    floatx4 accab = {};
    const float* xrow = x + (size_t)(i0 + m) * C_IN + q * 8;
    const float* absrc = (m == 0) ? ut : up;
    #pragma unroll
    for (int ks = 0; ks < 4; ++ks) {
        int k0 = (wv * 4 + ks) * 32;
        float4 f0 = *(const float4*)(xrow + k0);
        float4 f1 = *(const float4*)(xrow + k0 + 4);
        short8 af;
        af[0] = bf16rnd(f0.x); af[1] = bf16rnd(f0.y);
        af[2] = bf16rnd(f0.z); af[3] = bf16rnd(f0.w);
        af[4] = bf16rnd(f1.x); af[5] = bf16rnd(f1.y);
        af[6] = bf16rnd(f1.z); af[7] = bf16rnd(f1.w);
        if (cg == 0) {
            short8 abf = {};
            if (m < 2) {
                float4 u0 = *(const float4*)(absrc + k0 + q * 8);
                float4 u1 = *(const float4*)(absrc + k0 + q * 8 + 4);
                abf[0] = bf16rnd(u0.x); abf[1] = bf16rnd(u0.y);
                abf[2] = bf16rnd(u0.z); abf[3] = bf16rnd(u0.w);
                abf[4] = bf16rnd(u1.x); abf[5] = bf16rnd(u1.y);
                abf[6] = bf16rnd(u1.z); abf[7] = bf16rnd(u1.w);
            }
            accab = __builtin_amdgcn_mfma_f32_16x16x32_bf16(af, abf, accab, 0, 0, 0);
        }
        #pragma unroll
        for (int f = 0; f < 4; ++f) {
            short8 bfr = *(const short8*)(WgT + (size_t)(cg * 64 + f * 16 + m) * C_IN + k0 + q * 8);
            accg[f] = __builtin_amdgcn_mfma_f32_16x16x32_bf16(af, bfr, accg[f], 0, 0, 0);
        }
    }
    if (wv) {
        #pragma unroll
        for (int f = 0; f < 4; ++f)
            #pragma unroll
            for (int r = 0; r < 4; ++r)
                red[wv - 1][f * 4 + r][lane] = accg[f][r];
        #pragma unroll
        for (int r = 0; r < 4; ++r)
            red[wv - 1][16 + r][lane] = accab[r];
    }
    __syncthreads();
    if (wv == 0) {
        #pragma unroll
        for (int w = 0; w < 3; ++w) {
            #pragma unroll
            for (int f = 0; f < 4; ++f)
                #pragma unroll
                for (int r = 0; r < 4; ++r)
                    accg[f][r] += red[w][f * 4 + r][lane];
            #pragma unroll
            for (int r = 0; r < 4; ++r)
                accab[r] += red[w][16 + r][lane];
        }
        #pragma unroll
        for (int f = 0; f < 4; ++f) {
            int col = cg * 64 + f * 16 + m;
            float bgv = bg[col];
            #pragma unroll
            for (int r = 0; r < 4; ++r) {
                int row = i0 + q * 4 + r;
                g[(size_t)row * C_INT + col] = (_Float16)(accg[f][r] + bgv);
            }
        }
        if (cg == 0 && m < 2) {
            float off = m ? scal[1] : scal[0];
            float* dst = m ? b : a;
            #pragma unroll
            for (int r = 0; r < 4; ++r) dst[i0 + q * 4 + r] = accab[r] + off;
        }
    }
}

// ---------- K3: postA — per-block self-sort + own-segment sums + perm publish ----------
// 256 blocks x 1024 thr. Segments are BUCKET-ALIGNED (32 buckets each), so every
// block's deterministic bucket assignment yields identical per-segment row SETS;
// each bucket is published by exactly one block -> globally consistent perm.

__global__ __launch_bounds__(1024) void postA_kernel(
        const _Float16* __restrict__ g, const float* __restrict__ b,
        float* __restrict__ scal,
        unsigned* __restrict__ offs_g, unsigned short* __restrict__ perm_g,
        float* __restrict__ bsort_g,
        float* __restrict__ seg1, float* __restrict__ seg2) {
    __shared__ unsigned oh[NBUCK / 2];     // packed u16 pairs: hist -> inclusive scan
    __shared__ unsigned cur[NBUCK / 2];
    __shared__ unsigned short ls[8192];
    __shared__ unsigned wtu[16];
    __shared__ float smn[16], smx[16];
    __shared__ float part1[8][128], part2[8][128];
    int t = threadIdx.x, s = blockIdx.x;
    int lane = t & 63, wv = t >> 6;
    #pragma unroll
    for (int r = 0; r < 4; ++r) { oh[t + r * 1024] = 0u; cur[t + r * 1024] = 0u; }
    // load b; exact min/max (identical in every block -> identical buckets)
    float bv[8];
    float mn = 1e30f, mx = -1e30f;
    #pragma unroll
    for (int r = 0; r < 8; ++r) {
        bv[r] = b[t + r * 1024];
        mn = fminf(mn, bv[r]); mx = fmaxf(mx, bv[r]);
    }
    for (int off = 32; off; off >>= 1) {
        mn = fminf(mn, __shfl_down(mn, off));
        mx = fmaxf(mx, __shfl_down(mx, off));
    }
    if (lane == 0) { smn[wv] = mn; smx[wv] = mx; }
    __syncthreads();
    if (t == 0) {
        float gmn = smn[0], gmx = smx[0];
        #pragma unroll
        for (int i = 1; i < 16; ++i) {
            gmn = fminf(gmn, smn[i]); gmx = fmaxf(gmx, smx[i]);
        }
        float range = gmx - gmn;
        float iw = (range > 1e-30f) ? (float)NBUCK / range : 0.f;
        smn[0] = gmn; smx[0] = iw;
        if (s == 0) { scal[4] = gmn; scal[5] = iw; }
    }
    __syncthreads();
    float bmin = smn[0], inv_w = smx[0];
    int kb[8];
    #pragma unroll
    for (int r = 0; r < 8; ++r) {
        kb[r] = bucket_of(bv[r], bmin, inv_w);
        atomicAdd(&oh[kb[r] >> 1], (kb[r] & 1) ? 0x10000u : 1u);
    }
    __syncthreads();
    // inclusive scan of hist (packed)
    unsigned h[8], p0 = 0;
    #pragma unroll
    for (int w = 0; w < 4; ++w) {
        unsigned word = oh[t * 4 + w];
        p0 += word & 0xffffu;  h[w * 2]     = p0;
        p0 += word >> 16;      h[w * 2 + 1] = p0;
    }
    unsigned v = p0;
    #pragma unroll
    for (int d = 1; d < 64; d <<= 1) {
        unsigned u = __shfl_up(v, d);
        if (lane >= d) v += u;
    }
    if (lane == 63) wtu[wv] = v;
    __syncthreads();
    if (t < 16) {
        unsigned w = wtu[t];
        #pragma unroll
        for (int d = 1; d < 16; d <<= 1) {
            unsigned u = __shfl_up(w, d);
            if (t >= d) w += u;
        }
        wtu[t] = w;
    }
    __syncthreads();
    unsigned base = (v - p0) + (wv ? wtu[wv - 1] : 0u);
    #pragma unroll
    for (int w = 0; w < 4; ++w) {
        unsigned lo = base + h[w * 2], hi = base + h[w * 2 + 1];
        oh[t * 4 + w] = lo | (hi << 16);
        if (s == 0) {
            offs_g[t * 8 + w * 2 + 1] = lo;
            offs_g[t * 8 + w * 2 + 2] = hi;
        }
    }
    if (s == 0 && t == 0) offs_g[0] = 0u;
    __syncthreads();
    // scatter
    #pragma unroll
    for (int r = 0; r < 8; ++r) {
        int j = t + r * 1024;
        int k = kb[r];
        unsigned st = 0u;
        if (k > 0) {
            unsigned word = oh[(k - 1) >> 1];
            st = ((k - 1) & 1) ? (word >> 16) : (word & 0xffffu);
        }
        unsigned old = atomicAdd(&cur[k >> 1], (k & 1) ? 0x10000u : 1u);
        unsigned pos = (k & 1) ? (old >> 16) : (old & 0xffffu);
        ls[st + pos] = (unsigned short)j;
    }
    __syncthreads();
    // own-segment range [E0, E1): buckets s*BPS .. (s+1)*BPS
    auto incl = [&](int kk) -> unsigned {   // inclusive count through bucket kk
        unsigned word = oh[kk >> 1];
        return (kk & 1) ? (word >> 16) : (word & 0xffffu);
    };
    unsigned E0 = (s == 0) ? 0u : incl(s * BPS - 1);
    unsigned E1 = incl((s + 1) * BPS - 1);
    // publish own slice of perm/bsort (each bucket belongs to exactly one segment)
    for (unsigned e = E0 + t; e < E1; e += 1024) {
        int j = ls[e];
        perm_g[e] = (unsigned short)j;
        bsort_g[e] = b[j];
    }
    // own-segment sums, 8 parts x 128 channels
    int c = t & 127, p = t >> 7;
    float a1 = 0.f, a2 = 0.f;
    for (unsigned e = E0 + p; e < E1; e += 8) {
        int j = ls[e];
        float gv = (float)g[(size_t)j * C_INT + c];
        a1 += gv; a2 += b[j] * gv;
    }
    part1[p][c] = a1; part2[p][c] = a2;
    __syncthreads();
    if (p == 0) {
        float t1 = 0.f, t2 = 0.f;
        #pragma unroll
        for (int pp = 0; pp < 8; ++pp) { t1 += part1[pp][c]; t2 += part2[pp][c]; }
        seg1[s * C_INT + c] = t1;
        seg2[s * C_INT + c] = t2;
    }
}

// ---------- K4: postB — seg-suffix + walk own (variable-length) segment -> Pr ----------

__global__ __launch_bounds__(128) void postB_kernel(
        const _Float16* __restrict__ g, const unsigned* __restrict__ offs,
        const unsigned short* __restrict__ perm, const float* __restrict__ bsort,
        const float* __restrict__ seg1, const float* __restrict__ seg2,
        float* __restrict__ Pr1, float* __restrict__ Pr2) {
    __shared__ int pj[128];
    __shared__ float pb[128];
    int s = blockIdx.x, c = threadIdx.x;
    unsigned E0 = offs[s * BPS], E1 = offs[(s + 1) * BPS];
    float r1 = 0.f, r2 = 0.f;
    for (int s2 = s + 1; s2 < NSEG; ++s2) {
        r1 += seg1[s2 * C_INT + c];
        r2 += seg2[s2 * C_INT + c];
    }
    // walk own rows backwards, chunked staging (avg 32 rows)
    unsigned e = E1;
    while (e > E0) {
        unsigned cb = (e >= E0 + 128u) ? e - 128u : E0;
        unsigned cnt = e - cb;
        if ((unsigned)c < cnt) { pj[c] = perm[cb + c]; pb[c] = bsort[cb + c]; }
        __syncthreads();
        for (int r = (int)cnt - 1; r >= 0; --r) {
            float gv = (float)g[(size_t)pj[r] * C_INT + c];
            r1 += gv; r2 += pb[r] * gv;
            size_t idx = (size_t)(cb + r) * C_INT + c;
            Pr1[idx] = r1; Pr2[idx] = r2;
        }
        __syncthreads();
        e = cb;
    }
    if (s == 0) {
        Pr1[(size_t)8192 * C_INT + c] = 0.f;
        Pr2[(size_t)8192 * C_INT + c] = 0.f;
    }
}

// ---------- K5: per-row output (verified r7/r11, unchanged) ----------

__global__ __launch_bounds__(128) void out_kernel(
        const float* __restrict__ a, const float* __restrict__ scal,
        const _Float16* __restrict__ g,
        const unsigned* __restrict__ offs, const unsigned short* __restrict__ perm,
        const float* __restrict__ bsort,
        const float* __restrict__ Pr1, const float* __restrict__ Pr2,
        float* __restrict__ out, float inv_n) {
    __shared__ int pj[128];
    __shared__ float pb[128];
    int i = blockIdx.x, c = threadIdx.x;
    float ai = a[i], thr = -ai;
    float bmin = scal[4], inv_w = scal[5];
    int ki = bucket_of(thr, bmin, inv_w);
    unsigned e0 = offs[ki], e1 = offs[ki + 1];
    size_t base = (size_t)e1 * C_INT + c;
    float acc = ai * Pr1[base] + Pr2[base];
    for (unsigned be = e0; be < e1; be += 128) {
        unsigned cnt = min(128u, e1 - be);
        if ((unsigned)c < cnt) { pj[c] = perm[be + c]; pb[c] = bsort[be + c]; }
        __syncthreads();
        for (unsigned r = 0; r < cnt; ++r) {
            float bj = pb[r];
            if (bj > thr)
                acc += (ai + bj) * (float)g[(size_t)pj[r] * C_INT + c];
        }
        __syncthreads();
    }
    out[(size_t)i * C_INT + c] = acc * inv_n;
}

// ---------- launch ----------

extern "C" void kernel_launch(void* const* d_in, const int* in_sizes, int n_in,
                              void* d_out, int out_size, void* d_ws, size_t ws_size,
                              hipStream_t stream) {
    const float* x    = (const float*)d_in[0];
    const float* Wg   = (const float*)d_in[1];
    const float* bg   = (const float*)d_in[2];
    const float* Wt   = (const float*)d_in[3];
    const float* bt   = (const float*)d_in[4];
    const float* Wp   = (const float*)d_in[5];
    const float* bp   = (const float*)d_in[6];
    const float* wcat = (const float*)d_in[7];
    float* out = (float*)d_out;
    int n = in_sizes[0] / C_IN;   // 8192

    char* w = (char*)d_ws;
    size_t off = 0;
    auto alloc = [&](size_t bytes) -> void* {
        void* p = w + off;
        off += (bytes + 255) & ~(size_t)255;
        return p;
    };
    float*          ut    = (float*)alloc(C_IN * 4);
    float*          up    = (float*)alloc(C_IN * 4);
    float*          scal  = (float*)alloc(32);
    float*          a     = (float*)alloc((size_t)n * 4);
    float*          b     = (float*)alloc((size_t)n * 4);
    unsigned*       offs  = (unsigned*)alloc((size_t)(NBUCK + 1) * 4);
    unsigned short* perm  = (unsigned short*)alloc((size_t)n * 2);
    float*          bsort = (float*)alloc((size_t)n * 4);
    _Float16*       g     = (_Float16*)alloc((size_t)n * C_INT * 2);
    unsigned short* WgT   = (unsigned short*)alloc((size_t)C_INT * C_IN * 2);
    float*          seg1  = (float*)alloc((size_t)NSEG * C_INT * 4);
    float*          seg2  = (float*)alloc((size_t)NSEG * C_INT * 4);
    float*          Pr1   = (float*)alloc((size_t)(n + 1) * C_INT * 4);
    float*          Pr2   = (float*)alloc((size_t)(n + 1) * C_INT * 4);

    prep_kernel<<<25, 256, 0, stream>>>(Wt, Wp, Wg, wcat, bt, bp, ut, up, scal, WgT);
    gemm_mfma<<<n / 8, 256, 0, stream>>>(x, WgT, bg, ut, up, scal, g, a, b);
    postA_kernel<<<NSEG, 1024, 0, stream>>>(g, b, scal, offs, perm, bsort, seg1, seg2);
    postB_kernel<<<NSEG, 128, 0, stream>>>(g, offs, perm, bsort, seg1, seg2, Pr1, Pr2);
    out_kernel<<<n, 128, 0, stream>>>(a, scal, g, offs, perm, bsort, Pr1, Pr2,
                                      out, 1.0f / (float)n);
}